// Round 3
// baseline (147.424 us; speedup 1.0000x reference)
//
#include <hip/hip_runtime.h>
#include <hip/hip_bf16.h>

typedef __attribute__((ext_vector_type(8))) short short8;
typedef __attribute__((ext_vector_type(4))) float f32x4;
typedef __attribute__((ext_vector_type(2))) float f32x2;

#define M_TOTAL 131072
#define K_DIM 512
#define N_DIM 128
#define BM 128
#define BK 64
#define HALF 65536
#define MMD_BLOCKS 8192

// XOR swizzle within a 128-byte LDS row: spreads same-column reads of 8
// consecutive rows across 8 distinct 16B slots -> conflict-free ds_read_b128.
#define SWZ(r, byte) ((byte) ^ (((r) & 7) << 4))

__device__ __forceinline__ short bf16_bits(float f) {
    __hip_bfloat16 h = __float2bfloat16(f);
    return __builtin_bit_cast(short, h);
}

__device__ __forceinline__ short8 cvt8(f32x4 a, f32x4 b) {
    short8 p;
    p[0] = bf16_bits(a[0]); p[1] = bf16_bits(a[1]);
    p[2] = bf16_bits(a[2]); p[3] = bf16_bits(a[3]);
    p[4] = bf16_bits(b[0]); p[5] = bf16_bits(b[1]);
    p[6] = bf16_bits(b[2]); p[7] = bf16_bits(b[3]);
    return p;
}

// ---------------- W -> W^T bf16 prep ----------------------------------------
__global__ void __launch_bounds__(256) wt_prep_kernel(
    const float* __restrict__ W, __hip_bfloat16* __restrict__ Wt)
{
    int idx = blockIdx.x * 256 + threadIdx.x;   // 65536 total
    int k = idx >> 7;        // 0..511
    int n = idx & 127;       // 0..127
    Wt[n * K_DIM + k] = __float2bfloat16(W[idx]);
}

// ---------------- GEMM: out = relu(x @ W + b), bf16 MFMA ---------------------
__global__ void __launch_bounds__(256) gemm_relu_kernel(
    const float* __restrict__ x, const __hip_bfloat16* __restrict__ Wt,
    const float* __restrict__ bias, float* __restrict__ out)
{
    __shared__ char xs[BM * 128];     // 16 KB: x tile bf16 [128][64], swizzled
    __shared__ char ws[N_DIM * 128];  // 16 KB: W^T tile bf16 [128][64], swizzled

    const int tid  = threadIdx.x;
    const int lane = tid & 63;
    const int wave = tid >> 6;          // 4 waves: 2x2 grid of 64x64 sub-tiles
    const int wrow = (wave & 1) * 64;
    const int wcol = (wave >> 1) * 64;
    const long row0 = (long)blockIdx.x * BM;

    f32x4 acc[4][4];
#pragma unroll
    for (int m = 0; m < 4; ++m)
#pragma unroll
        for (int n = 0; n < 4; ++n) acc[m][n] = (f32x4)(0.0f);

    // staging assignments
    const int xr = tid >> 2;            // x row 0..63 (and +64)
    const int xc = (tid & 3) * 16;      // x f32 col base {0,16,32,48}
    const int wr = tid >> 1;            // Wt row 0..127
    const int wc = (tid & 1) * 32;      // Wt bf16 col base {0,32}

    const int frow = lane & 15;         // fragment row / col
    const int kg   = (lane >> 4) * 8;   // fragment k-group

    for (int kt = 0; kt < K_DIM; kt += BK) {
        if (kt) __syncthreads();
        // ---- stage x tile: coalesced f32 loads -> bf16 -> swizzled LDS ----
#pragma unroll
        for (int i = 0; i < 2; ++i) {
            const int r = xr + i * 64;
            const float* src = x + (row0 + r) * (long)K_DIM + kt + xc;
            f32x4 f0 = __builtin_nontemporal_load((const f32x4*)(src));
            f32x4 f1 = __builtin_nontemporal_load((const f32x4*)(src + 4));
            f32x4 f2 = __builtin_nontemporal_load((const f32x4*)(src + 8));
            f32x4 f3 = __builtin_nontemporal_load((const f32x4*)(src + 12));
            char* dst = xs + r * 128;
            *(short8*)(dst + SWZ(r, xc * 2))      = cvt8(f0, f1);
            *(short8*)(dst + SWZ(r, xc * 2 + 16)) = cvt8(f2, f3);
        }
        // ---- stage W^T tile (already bf16) ----
        {
            const short8* src = (const short8*)(Wt + (long)wr * K_DIM + kt + wc);
            char* dst = ws + wr * 128;
#pragma unroll
            for (int j = 0; j < 4; ++j)
                *(short8*)(dst + SWZ(wr, wc * 2 + j * 16)) = src[j];
        }
        __syncthreads();

        // ---- two K=32 sub-steps of MFMA ----
#pragma unroll
        for (int kk = 0; kk < 2; ++kk) {
            short8 af[4], bfv[4];
#pragma unroll
            for (int m = 0; m < 4; ++m) {
                const int r = wrow + m * 16 + frow;
                af[m] = *(const short8*)(xs + r * 128 + SWZ(r, kk * 64 + kg * 2));
            }
#pragma unroll
            for (int n = 0; n < 4; ++n) {
                const int r = wcol + n * 16 + frow;
                bfv[n] = *(const short8*)(ws + r * 128 + SWZ(r, kk * 64 + kg * 2));
            }
#pragma unroll
            for (int m = 0; m < 4; ++m)
#pragma unroll
                for (int n = 0; n < 4; ++n)
                    acc[m][n] = __builtin_amdgcn_mfma_f32_16x16x32_bf16(
                        af[m], bfv[n], acc[m][n], 0, 0, 0);
        }
    }

    // epilogue: bias + relu + store (C/D layout: col=lane&15, row=(lane>>4)*4+reg)
    float bv[4];
#pragma unroll
    for (int n = 0; n < 4; ++n) bv[n] = bias[wcol + n * 16 + frow];
    const int colb = wcol + frow;
    const long rowb = row0 + wrow + ((lane >> 4) * 4);
#pragma unroll
    for (int m = 0; m < 4; ++m)
#pragma unroll
        for (int j = 0; j < 4; ++j) {
            float* orow = out + (rowb + m * 16 + j) * N_DIM;
#pragma unroll
            for (int n = 0; n < 4; ++n)
                orow[colb + n * 16] = fmaxf(acc[m][n][j] + bv[n], 0.0f);
        }
}

// ---------------- MMD: one wave per pair ------------------------------------
__device__ __forceinline__ float mk8(float D) {
    float s = 0.0f;
#pragma unroll
    for (int k = 0; k < 8; ++k) {
        const float invg = 16.0f / (float)(1 << k);  // 1/gamma_k, gamma_k=2^(k-4)
        s += expf(-D * invg);
    }
    return s * 0.125f;
}

__global__ void __launch_bounds__(256) mmd_partial_kernel(
    const float* __restrict__ out, double* __restrict__ partials)
{
    __shared__ float gs[4];
    const int tid  = threadIdx.x;
    const int lane = tid & 63;
    const int wv   = tid >> 6;
    const long p   = (long)blockIdx.x * 4 + wv;   // pair index, 32768 total

    const float* s0 = out + (2 * p) * N_DIM + 2 * lane;
    const float* s1 = s0 + N_DIM;
    const float* t0 = out + ((long)HALF + 2 * p) * N_DIM + 2 * lane;
    const float* t1 = t0 + N_DIM;

    f32x2 a0 = *(const f32x2*)s0;
    f32x2 a1 = *(const f32x2*)s1;
    f32x2 b0 = *(const f32x2*)t0;
    f32x2 b1 = *(const f32x2*)t1;

    float dss = (a0[0]-a1[0])*(a0[0]-a1[0]) + (a0[1]-a1[1])*(a0[1]-a1[1]);
    float dtt = (b0[0]-b1[0])*(b0[0]-b1[0]) + (b0[1]-b1[1])*(b0[1]-b1[1]);
    float dst = (a0[0]-b1[0])*(a0[0]-b1[0]) + (a0[1]-b1[1])*(a0[1]-b1[1]);
    float dts = (a1[0]-b0[0])*(a1[0]-b0[0]) + (a1[1]-b0[1])*(a1[1]-b0[1]);

#pragma unroll
    for (int off = 32; off; off >>= 1) {
        dss += __shfl_xor(dss, off, 64);
        dtt += __shfl_xor(dtt, off, 64);
        dst += __shfl_xor(dst, off, 64);
        dts += __shfl_xor(dts, off, 64);
    }

    float g = mk8(dss) + mk8(dtt) - mk8(dst) - mk8(dts);
    if (lane == 0) gs[wv] = g;
    __syncthreads();
    if (tid == 0)
        partials[blockIdx.x] = (double)gs[0] + (double)gs[1] +
                               (double)gs[2] + (double)gs[3];
}

__global__ void __launch_bounds__(256) mmd_reduce_kernel(
    const double* __restrict__ partials, float* __restrict__ loss)
{
    __shared__ double sd[256];
    const int tid = threadIdx.x;
    double s = 0.0;
    for (int i = tid; i < MMD_BLOCKS; i += 256) s += partials[i];
    sd[tid] = s;
    __syncthreads();
    for (int w = 128; w; w >>= 1) {
        if (tid < w) sd[tid] += sd[tid + w];
        __syncthreads();
    }
    if (tid == 0) loss[0] = (float)(sd[0] * (2.0 / 65536.0));
}

extern "C" void kernel_launch(void* const* d_in, const int* in_sizes, int n_in,
                              void* d_out, int out_size, void* d_ws, size_t ws_size,
                              hipStream_t stream) {
    const float* x = (const float*)d_in[0];
    const float* W = (const float*)d_in[1];
    const float* b = (const float*)d_in[2];
    float* out = (float*)d_out;                         // 131072*128 + 1 floats

    __hip_bfloat16* Wt = (__hip_bfloat16*)d_ws;                       // 128 KB
    double* partials = (double*)((char*)d_ws + 131072);               // 64 KB

    wt_prep_kernel<<<256, 256, 0, stream>>>(W, Wt);
    gemm_relu_kernel<<<1024, 256, 0, stream>>>(x, Wt, b, out);
    mmd_partial_kernel<<<MMD_BLOCKS, 256, 0, stream>>>(out, partials);
    mmd_reduce_kernel<<<1, 256, 0, stream>>>(partials,
                                             out + (long)M_TOTAL * N_DIM);
}

// Round 4
// 118.675 us; speedup vs baseline: 1.2422x; 1.2422x over previous
//
#include <hip/hip_runtime.h>
#include <hip/hip_bf16.h>

typedef __attribute__((ext_vector_type(8))) short short8;
typedef __attribute__((ext_vector_type(4))) float f32x4;
typedef __attribute__((ext_vector_type(2))) float f32x2;

#define M_TOTAL 131072
#define K_DIM 512
#define N_DIM 128
#define BM 128
#define BK 32
#define HALF 65536
#define MMD_BLOCKS 8192

// LDS row stride in BYTES. 32 bf16 = 64 B data + 16 B pad = 80 B.
// 80 = 5*16 keeps every row 16B-aligned for ds_read_b128/ds_write_b128;
// 80*r mod 128 walks all eight 16B slots across 8 consecutive rows ->
// fragment reads (16 rows x fixed 16B column) are bank-conflict-free.
#define LDS_STRIDE 80

__device__ __forceinline__ short bf16_bits(float f) {
    __hip_bfloat16 h = __float2bfloat16(f);
    return __builtin_bit_cast(short, h);
}

__device__ __forceinline__ short8 cvt8(f32x4 a, f32x4 b) {
    short8 p;
    p[0] = bf16_bits(a[0]); p[1] = bf16_bits(a[1]);
    p[2] = bf16_bits(a[2]); p[3] = bf16_bits(a[3]);
    p[4] = bf16_bits(b[0]); p[5] = bf16_bits(b[1]);
    p[6] = bf16_bits(b[2]); p[7] = bf16_bits(b[3]);
    return p;
}

// ---------------- W -> W^T bf16 prep (one-time per call, 64K elems) ----------
__global__ void __launch_bounds__(256) wt_prep_kernel(
    const float* __restrict__ W, __hip_bfloat16* __restrict__ Wt)
{
    int idx = blockIdx.x * 256 + threadIdx.x;   // 65536 total
    int k = idx >> 7;        // 0..511
    int n = idx & 127;       // 0..127
    Wt[n * K_DIM + k] = __float2bfloat16(W[idx]);
}

// ---------------- GEMM: out = relu(x @ W + b), bf16 MFMA ---------------------
__global__ void __launch_bounds__(256) gemm_relu_kernel(
    const float* __restrict__ x, const __hip_bfloat16* __restrict__ Wt,
    const float* __restrict__ bias, float* __restrict__ out)
{
    __shared__ char xa[BM * LDS_STRIDE];     // 10 KB: x tile bf16, padded rows
    __shared__ char wb[N_DIM * LDS_STRIDE];  // 10 KB: W^T tile bf16, padded rows

    const int tid  = threadIdx.x;
    const int lane = tid & 63;
    const int wave = tid >> 6;          // 4 waves: 2x2 grid of 64x64 sub-tiles
    const int wrow = (wave & 1) * 64;
    const int wcol = (wave >> 1) * 64;
    const long row0 = (long)blockIdx.x * BM;

    f32x4 acc[4][4];
#pragma unroll
    for (int m = 0; m < 4; ++m)
#pragma unroll
        for (int n = 0; n < 4; ++n) acc[m][n] = (f32x4)(0.0f);

    const int sr = tid >> 2;            // x stage row 0..63
    const int sc = (tid & 3) * 8;       // x stage col {0,8,16,24} (f32 units)
    const int wn = tid >> 1;            // Wt stage row 0..127
    const int wk = (tid & 1) * 16;      // Wt stage k {0,16} (bf16 units)

    const int frow = lane & 15;
    const int kg   = (lane >> 4) * 8;   // fragment k-group (bf16 units)

    for (int kt = 0; kt < K_DIM; kt += BK) {
        if (kt) __syncthreads();
        // stage x tile: f32 -> bf16, padded-row LDS
#pragma unroll
        for (int i = 0; i < 2; ++i) {
            const int rr = sr + i * 64;
            const float* src = x + (row0 + rr) * (long)K_DIM + kt + sc;
            f32x4 f0 = *(const f32x4*)(src);
            f32x4 f1 = *(const f32x4*)(src + 4);
            *(short8*)(xa + rr * LDS_STRIDE + sc * 2) = cvt8(f0, f1);
        }
        // stage W^T tile (already bf16)
        {
            const short8* src = (const short8*)(Wt + (long)wn * K_DIM + kt + wk);
            char* dst = wb + wn * LDS_STRIDE + wk * 2;
            *(short8*)(dst)      = src[0];
            *(short8*)(dst + 16) = src[1];
        }
        __syncthreads();

        short8 af[4], bfv[4];
#pragma unroll
        for (int m = 0; m < 4; ++m) {
            const int r = wrow + m * 16 + frow;
            af[m] = *(const short8*)(xa + r * LDS_STRIDE + kg * 2);
        }
#pragma unroll
        for (int n = 0; n < 4; ++n) {
            const int r = wcol + n * 16 + frow;
            bfv[n] = *(const short8*)(wb + r * LDS_STRIDE + kg * 2);
        }
#pragma unroll
        for (int m = 0; m < 4; ++m)
#pragma unroll
            for (int n = 0; n < 4; ++n)
                acc[m][n] = __builtin_amdgcn_mfma_f32_16x16x32_bf16(
                    af[m], bfv[n], acc[m][n], 0, 0, 0);
    }

    // epilogue: bias + relu + store (C/D layout: col=lane&15, row=(lane>>4)*4+reg)
    float bv[4];
#pragma unroll
    for (int n = 0; n < 4; ++n) bv[n] = bias[wcol + n * 16 + frow];
    const int colb = wcol + frow;
    const long rowb = row0 + wrow + ((lane >> 4) * 4);
#pragma unroll
    for (int m = 0; m < 4; ++m)
#pragma unroll
        for (int j = 0; j < 4; ++j) {
            float* orow = out + (rowb + m * 16 + j) * N_DIM;
#pragma unroll
            for (int n = 0; n < 4; ++n)
                orow[colb + n * 16] = fmaxf(acc[m][n][j] + bv[n], 0.0f);
        }
}

// ---------------- MMD: one wave per pair ------------------------------------
__device__ __forceinline__ float mk8(float D) {
    float s = 0.0f;
#pragma unroll
    for (int k = 0; k < 8; ++k) {
        const float invg = 16.0f / (float)(1 << k);  // 1/gamma_k, gamma_k=2^(k-4)
        s += expf(-D * invg);
    }
    return s * 0.125f;
}

__global__ void __launch_bounds__(256) mmd_partial_kernel(
    const float* __restrict__ out, double* __restrict__ partials)
{
    __shared__ float gs[4];
    const int tid  = threadIdx.x;
    const int lane = tid & 63;
    const int wv   = tid >> 6;
    const long p   = (long)blockIdx.x * 4 + wv;   // pair index, 32768 total

    const float* s0 = out + (2 * p) * N_DIM + 2 * lane;
    const float* s1 = s0 + N_DIM;
    const float* t0 = out + ((long)HALF + 2 * p) * N_DIM + 2 * lane;
    const float* t1 = t0 + N_DIM;

    f32x2 a0 = *(const f32x2*)s0;
    f32x2 a1 = *(const f32x2*)s1;
    f32x2 b0 = *(const f32x2*)t0;
    f32x2 b1 = *(const f32x2*)t1;

    float dss = (a0[0]-a1[0])*(a0[0]-a1[0]) + (a0[1]-a1[1])*(a0[1]-a1[1]);
    float dtt = (b0[0]-b1[0])*(b0[0]-b1[0]) + (b0[1]-b1[1])*(b0[1]-b1[1]);
    float dst = (a0[0]-b1[0])*(a0[0]-b1[0]) + (a0[1]-b1[1])*(a0[1]-b1[1]);
    float dts = (a1[0]-b0[0])*(a1[0]-b0[0]) + (a1[1]-b0[1])*(a1[1]-b0[1]);

#pragma unroll
    for (int off = 32; off; off >>= 1) {
        dss += __shfl_xor(dss, off, 64);
        dtt += __shfl_xor(dtt, off, 64);
        dst += __shfl_xor(dst, off, 64);
        dts += __shfl_xor(dts, off, 64);
    }

    float g = mk8(dss) + mk8(dtt) - mk8(dst) - mk8(dts);
    if (lane == 0) gs[wv] = g;
    __syncthreads();
    if (tid == 0)
        partials[blockIdx.x] = (double)gs[0] + (double)gs[1] +
                               (double)gs[2] + (double)gs[3];
}

__global__ void __launch_bounds__(256) mmd_reduce_kernel(
    const double* __restrict__ partials, float* __restrict__ loss)
{
    __shared__ double sd[256];
    const int tid = threadIdx.x;
    double s = 0.0;
    for (int i = tid; i < MMD_BLOCKS; i += 256) s += partials[i];
    sd[tid] = s;
    __syncthreads();
    for (int w = 128; w; w >>= 1) {
        if (tid < w) sd[tid] += sd[tid + w];
        __syncthreads();
    }
    if (tid == 0) loss[0] = (float)(sd[0] * (2.0 / 65536.0));
}

extern "C" void kernel_launch(void* const* d_in, const int* in_sizes, int n_in,
                              void* d_out, int out_size, void* d_ws, size_t ws_size,
                              hipStream_t stream) {
    const float* x = (const float*)d_in[0];
    const float* W = (const float*)d_in[1];
    const float* b = (const float*)d_in[2];
    float* out = (float*)d_out;                         // 131072*128 + 1 floats

    __hip_bfloat16* Wt = (__hip_bfloat16*)d_ws;                       // 128 KB
    double* partials = (double*)((char*)d_ws + 131072);               // 64 KB

    wt_prep_kernel<<<256, 256, 0, stream>>>(W, Wt);
    gemm_relu_kernel<<<1024, 256, 0, stream>>>(x, Wt, b, out);
    mmd_partial_kernel<<<MMD_BLOCKS, 256, 0, stream>>>(out, partials);
    mmd_reduce_kernel<<<1, 256, 0, stream>>>(partials,
                                             out + (long)M_TOTAL * N_DIM);
}

// Round 5
// 103.134 us; speedup vs baseline: 1.4294x; 1.1507x over previous
//
#include <hip/hip_runtime.h>
#include <hip/hip_bf16.h>

typedef __attribute__((ext_vector_type(8))) short short8;
typedef __attribute__((ext_vector_type(4))) float f32x4;
typedef __attribute__((ext_vector_type(2))) float f32x2;

#define M_TOTAL 131072
#define K_DIM 512
#define N_DIM 128
#define BM 128
#define BK 32
#define HALF 65536
#define MMD_BLOCKS 8192
#define KSTEPS 16

// 32 bf16 = 64 B data + 16 B pad = 80 B rows (16B-aligned, conflict-benign)
#define LDS_STRIDE 80

__device__ __forceinline__ short bf16_bits(float f) {
    __hip_bfloat16 h = __float2bfloat16(f);
    return __builtin_bit_cast(short, h);
}

__device__ __forceinline__ short8 cvt8(f32x4 a, f32x4 b) {
    short8 p;
    p[0] = bf16_bits(a[0]); p[1] = bf16_bits(a[1]);
    p[2] = bf16_bits(a[2]); p[3] = bf16_bits(a[3]);
    p[4] = bf16_bits(b[0]); p[5] = bf16_bits(b[1]);
    p[6] = bf16_bits(b[2]); p[7] = bf16_bits(b[3]);
    return p;
}

// ---------------- W -> W^T bf16 prep ----------------------------------------
__global__ void __launch_bounds__(256) wt_prep_kernel(
    const float* __restrict__ W, __hip_bfloat16* __restrict__ Wt)
{
    int idx = blockIdx.x * 256 + threadIdx.x;   // 65536 total
    int k = idx >> 7;        // 0..511
    int n = idx & 127;       // 0..127
    Wt[n * K_DIM + k] = __float2bfloat16(W[idx]);
}

// ---- GEMM: out = relu(x @ W + b); double-buffered LDS, reg-prefetch --------
__global__ void __launch_bounds__(256) gemm_relu_kernel(
    const float* __restrict__ x, const __hip_bfloat16* __restrict__ Wt,
    const float* __restrict__ bias, float* __restrict__ out)
{
    __shared__ char xa[2][BM * LDS_STRIDE];     // 2 x 10 KB
    __shared__ char wb[2][N_DIM * LDS_STRIDE];  // 2 x 10 KB

    const int tid  = threadIdx.x;
    const int lane = tid & 63;
    const int wave = tid >> 6;          // 4 waves: 2x2 grid of 64x64 sub-tiles
    const int wrow = (wave & 1) * 64;
    const int wcol = (wave >> 1) * 64;
    const long row0 = (long)blockIdx.x * BM;

    f32x4 acc[4][4];
#pragma unroll
    for (int m = 0; m < 4; ++m)
#pragma unroll
        for (int n = 0; n < 4; ++n) acc[m][n] = (f32x4)(0.0f);

    const int sr = tid >> 2;            // x stage row 0..63 (and +64)
    const int sc = (tid & 3) * 8;       // x stage col {0,8,16,24} (f32)
    const int wn = tid >> 1;            // Wt stage row 0..127
    const int wk = (tid & 1) * 16;      // Wt stage k {0,16} (bf16)

    const int frow = lane & 15;
    const int kg   = (lane >> 4) * 8;

    const float* xsrc0 = x + (row0 + sr) * (long)K_DIM + sc;
    const float* xsrc1 = xsrc0 + 64 * (long)K_DIM;
    const __hip_bfloat16* wsrc = Wt + (long)wn * K_DIM + wk;

    // ---- prologue: stage tile 0 into buffer 0 ----
    f32x4 r00 = *(const f32x4*)(xsrc0);
    f32x4 r01 = *(const f32x4*)(xsrc0 + 4);
    f32x4 r10 = *(const f32x4*)(xsrc1);
    f32x4 r11 = *(const f32x4*)(xsrc1 + 4);
    short8 rw0 = *(const short8*)(wsrc);
    short8 rw1 = *(const short8*)(wsrc + 8);

    *(short8*)(xa[0] + sr * LDS_STRIDE + sc * 2)        = cvt8(r00, r01);
    *(short8*)(xa[0] + (sr + 64) * LDS_STRIDE + sc * 2) = cvt8(r10, r11);
    {
        char* wd = wb[0] + wn * LDS_STRIDE + wk * 2;
        *(short8*)(wd)      = rw0;
        *(short8*)(wd + 16) = rw1;
    }
    __syncthreads();

    for (int k = 0; k < KSTEPS; ++k) {
        const int cur = k & 1;
        const int nxt = cur ^ 1;
        const int kt  = (k + 1) * BK;

        // issue next tile's global loads (in flight during compute)
        if (k < KSTEPS - 1) {
            r00 = *(const f32x4*)(xsrc0 + kt);
            r01 = *(const f32x4*)(xsrc0 + kt + 4);
            r10 = *(const f32x4*)(xsrc1 + kt);
            r11 = *(const f32x4*)(xsrc1 + kt + 4);
            rw0 = *(const short8*)(wsrc + kt);
            rw1 = *(const short8*)(wsrc + kt + 8);
        }

        // compute current tile
        short8 af[4], bfv[4];
#pragma unroll
        for (int m = 0; m < 4; ++m) {
            const int r = wrow + m * 16 + frow;
            af[m] = *(const short8*)(xa[cur] + r * LDS_STRIDE + kg * 2);
        }
#pragma unroll
        for (int n = 0; n < 4; ++n) {
            const int r = wcol + n * 16 + frow;
            bfv[n] = *(const short8*)(wb[cur] + r * LDS_STRIDE + kg * 2);
        }
#pragma unroll
        for (int m = 0; m < 4; ++m)
#pragma unroll
            for (int n = 0; n < 4; ++n)
                acc[m][n] = __builtin_amdgcn_mfma_f32_16x16x32_bf16(
                    af[m], bfv[n], acc[m][n], 0, 0, 0);

        // stage next tile into alternate buffer
        if (k < KSTEPS - 1) {
            *(short8*)(xa[nxt] + sr * LDS_STRIDE + sc * 2)        = cvt8(r00, r01);
            *(short8*)(xa[nxt] + (sr + 64) * LDS_STRIDE + sc * 2) = cvt8(r10, r11);
            char* wd = wb[nxt] + wn * LDS_STRIDE + wk * 2;
            *(short8*)(wd)      = rw0;
            *(short8*)(wd + 16) = rw1;
        }
        __syncthreads();
    }

    // epilogue: bias + relu + store (C/D layout: col=lane&15, row=(lane>>4)*4+reg)
    float bv[4];
#pragma unroll
    for (int n = 0; n < 4; ++n) bv[n] = bias[wcol + n * 16 + frow];
    const int colb = wcol + frow;
    const long rowb = row0 + wrow + ((lane >> 4) * 4);
#pragma unroll
    for (int m = 0; m < 4; ++m)
#pragma unroll
        for (int j = 0; j < 4; ++j) {
            float* orow = out + (rowb + m * 16 + j) * N_DIM;
#pragma unroll
            for (int n = 0; n < 4; ++n)
                orow[colb + n * 16] = fmaxf(acc[m][n][j] + bv[n], 0.0f);
        }
}

// ---------------- MMD: one wave per pair, exp distributed over lanes --------
__global__ void __launch_bounds__(256) mmd_partial_kernel(
    const float* __restrict__ out, double* __restrict__ partials)
{
    __shared__ float gs[4];
    const int tid  = threadIdx.x;
    const int lane = tid & 63;
    const int wv   = tid >> 6;
    const long p   = (long)blockIdx.x * 4 + wv;   // pair index, 32768 total

    const float* s0 = out + (2 * p) * N_DIM + 2 * lane;
    const float* s1 = s0 + N_DIM;
    const float* t0 = out + ((long)HALF + 2 * p) * N_DIM + 2 * lane;
    const float* t1 = t0 + N_DIM;

    f32x2 a0 = *(const f32x2*)s0;
    f32x2 a1 = *(const f32x2*)s1;
    f32x2 b0 = *(const f32x2*)t0;
    f32x2 b1 = *(const f32x2*)t1;

    float D[4];
    D[0] = (a0[0]-a1[0])*(a0[0]-a1[0]) + (a0[1]-a1[1])*(a0[1]-a1[1]);
    D[1] = (b0[0]-b1[0])*(b0[0]-b1[0]) + (b0[1]-b1[1])*(b0[1]-b1[1]);
    D[2] = (a0[0]-b1[0])*(a0[0]-b1[0]) + (a0[1]-b1[1])*(a0[1]-b1[1]);
    D[3] = (a1[0]-b0[0])*(a1[0]-b0[0]) + (a1[1]-b0[1])*(a1[1]-b0[1]);

#pragma unroll
    for (int off = 32; off; off >>= 1) {
#pragma unroll
        for (int i = 0; i < 4; ++i) D[i] += __shfl_xor(D[i], off, 64);
    }

    // 32 signed exp terms distributed: lane t (mod 32) handles dist t>>3, gamma t&7
    const int t = lane & 31;
    const float invg = 16.0f / (float)(1 << (t & 7));   // 1/gamma_k
    float term = __expf(-D[t >> 3] * invg);
    term = (t < 16) ? term : -term;                     // ss,tt: + ; st,ts: -
#pragma unroll
    for (int off = 1; off <= 16; off <<= 1) term += __shfl_xor(term, off, 64);

    if (lane == 0) gs[wv] = term * 0.125f;
    __syncthreads();
    if (tid == 0)
        partials[blockIdx.x] = (double)gs[0] + (double)gs[1] +
                               (double)gs[2] + (double)gs[3];
}

__global__ void __launch_bounds__(256) mmd_reduce_kernel(
    const double* __restrict__ partials, float* __restrict__ loss)
{
    __shared__ double sd[256];
    const int tid = threadIdx.x;
    double s = 0.0;
    for (int i = tid; i < MMD_BLOCKS; i += 256) s += partials[i];
    sd[tid] = s;
    __syncthreads();
    for (int w = 128; w; w >>= 1) {
        if (tid < w) sd[tid] += sd[tid + w];
        __syncthreads();
    }
    if (tid == 0) loss[0] = (float)(sd[0] * (2.0 / 65536.0));
}

extern "C" void kernel_launch(void* const* d_in, const int* in_sizes, int n_in,
                              void* d_out, int out_size, void* d_ws, size_t ws_size,
                              hipStream_t stream) {
    const float* x = (const float*)d_in[0];
    const float* W = (const float*)d_in[1];
    const float* b = (const float*)d_in[2];
    float* out = (float*)d_out;                         // 131072*128 + 1 floats

    __hip_bfloat16* Wt = (__hip_bfloat16*)d_ws;                       // 128 KB
    double* partials = (double*)((char*)d_ws + 131072);               // 64 KB

    wt_prep_kernel<<<256, 256, 0, stream>>>(W, Wt);
    gemm_relu_kernel<<<1024, 256, 0, stream>>>(x, Wt, b, out);
    mmd_partial_kernel<<<MMD_BLOCKS, 256, 0, stream>>>(out, partials);
    mmd_reduce_kernel<<<1, 256, 0, stream>>>(partials,
                                             out + (long)M_TOTAL * N_DIM);
}

// Round 6
// 93.017 us; speedup vs baseline: 1.5849x; 1.1088x over previous
//
#include <hip/hip_runtime.h>
#include <hip/hip_bf16.h>

typedef __attribute__((ext_vector_type(8))) short short8;
typedef __attribute__((ext_vector_type(4))) float f32x4;

#define M_TOTAL 131072
#define K_DIM 512
#define N_DIM 128
#define BM 128
#define BK 32
#define HALF 65536
#define GBLOCKS 1024
#define KSTEPS 16

// 32 bf16 = 64 B data + 16 B pad = 80 B rows (16B-aligned)
#define LDS_STRIDE 80

__device__ __forceinline__ short bf16_bits(float f) {
    __hip_bfloat16 h = __float2bfloat16(f);
    return __builtin_bit_cast(short, h);
}

__device__ __forceinline__ short8 cvt8(f32x4 a, f32x4 b) {
    short8 p;
    p[0] = bf16_bits(a[0]); p[1] = bf16_bits(a[1]);
    p[2] = bf16_bits(a[2]); p[3] = bf16_bits(a[3]);
    p[4] = bf16_bits(b[0]); p[5] = bf16_bits(b[1]);
    p[6] = bf16_bits(b[2]); p[7] = bf16_bits(b[3]);
    return p;
}

// ---------------- W -> W^T bf16 prep ----------------------------------------
__global__ void __launch_bounds__(256) wt_prep_kernel(
    const float* __restrict__ W, __hip_bfloat16* __restrict__ Wt)
{
    int idx = blockIdx.x * 256 + threadIdx.x;   // 65536 total
    int k = idx >> 7;        // 0..511
    int n = idx & 127;       // 0..127
    Wt[n * K_DIM + k] = __float2bfloat16(W[idx]);
}

// ---- fused: relu(x@W+b) with R5 double-buffered MFMA core, + in-block MMD --
// Block b owns first-half rows [64b, 64b+64) (LDS rows 0..63) and
// second-half rows [HALF+64b, HALF+64b+64) (LDS rows 64..127).
__global__ void __launch_bounds__(256) gemm_relu_mmd_kernel(
    const float* __restrict__ x, const __hip_bfloat16* __restrict__ Wt,
    const float* __restrict__ bias, float* __restrict__ out,
    double* __restrict__ partials)
{
    __shared__ char xa[2][BM * LDS_STRIDE];     // 2 x 10 KB
    __shared__ char wb[2][N_DIM * LDS_STRIDE];  // 2 x 10 KB
    __shared__ float gsh[32];

    const int tid  = threadIdx.x;
    const int lane = tid & 63;
    const int wave = tid >> 6;          // 4 waves: 2x2 grid of 64x64 sub-tiles
    const int wrow = (wave & 1) * 64;
    const int wcol = (wave >> 1) * 64;
    const long blk = blockIdx.x;
    const long row0f = blk * 64;            // first-half base
    const long row0s = (long)HALF + blk * 64;   // second-half base

    f32x4 acc[4][4];
#pragma unroll
    for (int m = 0; m < 4; ++m)
#pragma unroll
        for (int n = 0; n < 4; ++n) acc[m][n] = (f32x4)(0.0f);

    const int sr = tid >> 2;            // x stage row 0..63
    const int sc = (tid & 3) * 8;       // x stage col {0,8,16,24} (f32)
    const int wn = tid >> 1;            // Wt stage row 0..127
    const int wk = (tid & 1) * 16;      // Wt stage k {0,16} (bf16)

    const int frow = lane & 15;
    const int kg   = (lane >> 4) * 8;

    const float* xsrc0 = x + (row0f + sr) * (long)K_DIM + sc;   // LDS rows 0..63
    const float* xsrc1 = x + (row0s + sr) * (long)K_DIM + sc;   // LDS rows 64..127
    const __hip_bfloat16* wsrc = Wt + (long)wn * K_DIM + wk;

    // ---- prologue: stage tile 0 into buffer 0 ----
    f32x4 r00 = *(const f32x4*)(xsrc0);
    f32x4 r01 = *(const f32x4*)(xsrc0 + 4);
    f32x4 r10 = *(const f32x4*)(xsrc1);
    f32x4 r11 = *(const f32x4*)(xsrc1 + 4);
    short8 rw0 = *(const short8*)(wsrc);
    short8 rw1 = *(const short8*)(wsrc + 8);

    *(short8*)(xa[0] + sr * LDS_STRIDE + sc * 2)        = cvt8(r00, r01);
    *(short8*)(xa[0] + (sr + 64) * LDS_STRIDE + sc * 2) = cvt8(r10, r11);
    {
        char* wd = wb[0] + wn * LDS_STRIDE + wk * 2;
        *(short8*)(wd)      = rw0;
        *(short8*)(wd + 16) = rw1;
    }
    __syncthreads();

    for (int k = 0; k < KSTEPS; ++k) {
        const int cur = k & 1;
        const int nxt = cur ^ 1;
        const int kt  = (k + 1) * BK;

        if (k < KSTEPS - 1) {
            r00 = *(const f32x4*)(xsrc0 + kt);
            r01 = *(const f32x4*)(xsrc0 + kt + 4);
            r10 = *(const f32x4*)(xsrc1 + kt);
            r11 = *(const f32x4*)(xsrc1 + kt + 4);
            rw0 = *(const short8*)(wsrc + kt);
            rw1 = *(const short8*)(wsrc + kt + 8);
        }

        short8 af[4], bfv[4];
#pragma unroll
        for (int m = 0; m < 4; ++m) {
            const int r = wrow + m * 16 + frow;
            af[m] = *(const short8*)(xa[cur] + r * LDS_STRIDE + kg * 2);
        }
#pragma unroll
        for (int n = 0; n < 4; ++n) {
            const int r = wcol + n * 16 + frow;
            bfv[n] = *(const short8*)(wb[cur] + r * LDS_STRIDE + kg * 2);
        }
#pragma unroll
        for (int m = 0; m < 4; ++m)
#pragma unroll
            for (int n = 0; n < 4; ++n)
                acc[m][n] = __builtin_amdgcn_mfma_f32_16x16x32_bf16(
                    af[m], bfv[n], acc[m][n], 0, 0, 0);

        if (k < KSTEPS - 1) {
            *(short8*)(xa[nxt] + sr * LDS_STRIDE + sc * 2)        = cvt8(r00, r01);
            *(short8*)(xa[nxt] + (sr + 64) * LDS_STRIDE + sc * 2) = cvt8(r10, r11);
            char* wd = wb[nxt] + wn * LDS_STRIDE + wk * 2;
            *(short8*)(wd)      = rw0;
            *(short8*)(wd + 16) = rw1;
        }
        __syncthreads();
    }

    // epilogue: bias + relu + store. Local row r<64 -> row0f+r ; r>=64 -> row0s+(r-64)
    float bv[4];
#pragma unroll
    for (int n = 0; n < 4; ++n) bv[n] = bias[wcol + n * 16 + frow];
    const int colb = wcol + frow;
    const long wbase = (wrow == 0) ? row0f : (row0s - 64);
    const long rowb = wbase + wrow + ((lane >> 4) * 4);
#pragma unroll
    for (int m = 0; m < 4; ++m)
#pragma unroll
        for (int j = 0; j < 4; ++j) {
            float* orow = out + (rowb + m * 16 + j) * N_DIM;
#pragma unroll
            for (int n = 0; n < 4; ++n)
                orow[colb + n * 16] = fmaxf(acc[m][n][j] + bv[n], 0.0f);
        }

    // ---- in-block MMD over the 32 pairs this block owns (L2-hot re-read) ---
    __threadfence_block();
    __syncthreads();

    const int pr  = tid >> 3;      // pair 0..31
    const int sub = tid & 7;       // 8 threads/pair, 16 dims each
    const float* r0 = out + (row0f + 2 * pr) * (long)N_DIM + sub * 16;  // s0
    const float* r1 = r0 + N_DIM;                                       // s1
    const float* r2 = out + (row0s + 2 * pr) * (long)N_DIM + sub * 16;  // t0
    const float* r3 = r2 + N_DIM;                                       // t1

    f32x4 vss = (f32x4)(0.f), vtt = (f32x4)(0.f), vst = (f32x4)(0.f), vts = (f32x4)(0.f);
#pragma unroll
    for (int c = 0; c < 4; ++c) {
        f32x4 a0 = *(const f32x4*)(r0 + 4 * c);
        f32x4 a1 = *(const f32x4*)(r1 + 4 * c);
        f32x4 b0 = *(const f32x4*)(r2 + 4 * c);
        f32x4 b1 = *(const f32x4*)(r3 + 4 * c);
        f32x4 d;
        d = a0 - a1; vss += d * d;
        d = b0 - b1; vtt += d * d;
        d = a0 - b1; vst += d * d;
        d = a1 - b0; vts += d * d;
    }
    float D[4];
    D[0] = vss[0] + vss[1] + vss[2] + vss[3];
    D[1] = vtt[0] + vtt[1] + vtt[2] + vtt[3];
    D[2] = vst[0] + vst[1] + vst[2] + vst[3];
    D[3] = vts[0] + vts[1] + vts[2] + vts[3];
#pragma unroll
    for (int off = 1; off <= 4; off <<= 1) {
#pragma unroll
        for (int i = 0; i < 4; ++i) D[i] += __shfl_xor(D[i], off, 64);
    }
    // 32 signed exp terms spread over the 8 threads of the pair (4 each)
    float part = 0.f;
#pragma unroll
    for (int j = 0; j < 4; ++j) {
        const int t  = sub * 4 + j;
        const int di = t >> 3;           // distance index 0..3
        const float invg = 16.0f / (float)(1 << (t & 7));   // 1/gamma_k
        const float e = __expf(-D[di] * invg);
        part += (di < 2) ? e : -e;
    }
#pragma unroll
    for (int off = 1; off <= 4; off <<= 1) part += __shfl_xor(part, off, 64);
    if (sub == 0) gsh[pr] = part * 0.125f;
    __syncthreads();
    if (tid == 0) {
        double s = 0.0;
#pragma unroll
        for (int i = 0; i < 32; ++i) s += (double)gsh[i];
        partials[blk] = s;
    }
}

__global__ void __launch_bounds__(256) mmd_reduce_kernel(
    const double* __restrict__ partials, float* __restrict__ loss)
{
    __shared__ double sd[256];
    const int tid = threadIdx.x;
    double s = 0.0;
    for (int i = tid; i < GBLOCKS; i += 256) s += partials[i];
    sd[tid] = s;
    __syncthreads();
    for (int w = 128; w; w >>= 1) {
        if (tid < w) sd[tid] += sd[tid + w];
        __syncthreads();
    }
    if (tid == 0) loss[0] = (float)(sd[0] * (2.0 / 65536.0));
}

extern "C" void kernel_launch(void* const* d_in, const int* in_sizes, int n_in,
                              void* d_out, int out_size, void* d_ws, size_t ws_size,
                              hipStream_t stream) {
    const float* x = (const float*)d_in[0];
    const float* W = (const float*)d_in[1];
    const float* b = (const float*)d_in[2];
    float* out = (float*)d_out;                         // 131072*128 + 1 floats

    __hip_bfloat16* Wt = (__hip_bfloat16*)d_ws;                 // 128 KB
    double* partials = (double*)((char*)d_ws + 131072);         // 8 KB

    wt_prep_kernel<<<256, 256, 0, stream>>>(W, Wt);
    gemm_relu_mmd_kernel<<<GBLOCKS, 256, 0, stream>>>(x, Wt, b, out, partials);
    mmd_reduce_kernel<<<1, 256, 0, stream>>>(partials, out + (long)M_TOTAL * N_DIM);
}